// Round 13
// baseline (403.716 us; speedup 1.0000x reference)
//
#include <hip/hip_runtime.h>
#include <hip/hip_bf16.h>
#include <math.h>

#define INPUT 2048
#define HIDDEN 128
#define BATCH 64
#define TSTEPS 512
#define RB 16

typedef _Float16 half_t;
typedef __attribute__((ext_vector_type(2))) _Float16 half2_t;
typedef __attribute__((ext_vector_type(8))) _Float16 f16x8;
typedef __attribute__((ext_vector_type(4))) float f32x4;

static __device__ __forceinline__ f16x8 as_f16x8(uint4 v) {
  return __builtin_bit_cast(f16x8, v);
}
static __device__ __forceinline__ unsigned int h2u(half2_t v) {
  return __builtin_bit_cast(unsigned int, v);
}
static __device__ __forceinline__ half2_t pkrtz(float a, float b) {
  return __builtin_bit_cast(half2_t, __builtin_amdgcn_cvt_pkrtz(a, b));
}
static __device__ __forceinline__ float h2f(unsigned short u) {
  return (float)__builtin_bit_cast(half_t, u);
}

// tanh(x) = 1 - 2/(e^{2x}+1); e^{2x} = 2^{x*2/ln2}. Saturates correctly.
static __device__ __forceinline__ float tanh_fast(float x) {
#if __has_builtin(__builtin_amdgcn_exp2f)
  const float e = __builtin_amdgcn_exp2f(x * 2.885390082f);
#else
  const float e = exp2f(x * 2.885390082f);
#endif
  return 1.f - 2.f * __builtin_amdgcn_rcpf(e + 1.f);
}

// ---------------------------------------------------------------------------
// Prep: W_ih f32 -> Wg granule layout; W_hh f32 -> packed half2 (k-major).
// ---------------------------------------------------------------------------
__global__ __launch_bounds__(256) void prep_kernel(
    const float* __restrict__ W_ih, const float* __restrict__ W_hh,
    uint4* __restrict__ Wg, unsigned int* __restrict__ Whh2) {
  const int id = blockIdx.x * 256 + threadIdx.x;  // 32768 threads
  const int col = id & 127;
  const int kc = id >> 7;  // 0..255
  const float4 a = *(const float4*)(W_ih + (size_t)col * INPUT + kc * 8);
  const float4 b = *(const float4*)(W_ih + (size_t)col * INPUT + kc * 8 + 4);
  uint4 q = {h2u(pkrtz(a.x, a.y)), h2u(pkrtz(a.z, a.w)),
             h2u(pkrtz(b.x, b.y)), h2u(pkrtz(b.z, b.w))};
  Wg[(size_t)kc * 128 + col] = q;
  if (id < 8192) {
    float2 p = ((const float2*)W_hh)[id];
    half_t ha = (half_t)p.x, hb = (half_t)p.y;
    Whh2[id] = (unsigned int)__builtin_bit_cast(unsigned short, ha) |
               ((unsigned int)__builtin_bit_cast(unsigned short, hb) << 16);
  }
}

// ---------------------------------------------------------------------------
// GEMM (R10/R11 form, measured ~70 us): A LDS-staged depth-2, B direct L2.
// ---------------------------------------------------------------------------
#define GBM 64
#define GBK 64
#define GNKT (INPUT / GBK)  // 32

__global__ __launch_bounds__(256) void gemm_xw_f16(
    const float* __restrict__ x, const uint4* __restrict__ Wg,
    const float* __restrict__ b_ih, const float* __restrict__ b_hh,
    half_t* __restrict__ xw) {
  __shared__ uint4 sA[2][8][64];  // [buf][kc][m]  16 KB

  const int tid = threadIdx.x;
  const int lane = tid & 63;
  const int w = tid >> 6;
  const int wr = w >> 1, wc = w & 1;
  const int block_row = blockIdx.x * GBM;
  const int kcl = lane >> 4;
  const int l15 = lane & 15;

  const int xm = tid & 63, xkq = tid >> 6;
  const float* xsrc = x + (size_t)(block_row + xm) * INPUT + xkq * 16;

  f32x4 acc[2][4];
#pragma unroll
  for (int rt = 0; rt < 2; ++rt)
#pragma unroll
    for (int ct = 0; ct < 4; ++ct) acc[rt][ct] = (f32x4)0.f;

  float bias_c[4];
#pragma unroll
  for (int ct = 0; ct < 4; ++ct) {
    const int col = wc * 64 + ct * 16 + l15;
    bias_c[ct] = b_ih[col] + b_hh[col];
  }

  float4 xva[4], xvb[4];
  uint4 br0[8], br1[8];

  auto XLOAD = [&](int kt, float4* xv) {
    const float4* xs = (const float4*)(xsrc + kt * GBK);
#pragma unroll
    for (int j = 0; j < 4; ++j) xv[j] = xs[j];
  };
  auto XWRITE = [&](int bf, const float4* xv) {
#pragma unroll
    for (int g = 0; g < 2; ++g) {
      uint4 q = {h2u(pkrtz(xv[2 * g].x, xv[2 * g].y)),
                 h2u(pkrtz(xv[2 * g].z, xv[2 * g].w)),
                 h2u(pkrtz(xv[2 * g + 1].x, xv[2 * g + 1].y)),
                 h2u(pkrtz(xv[2 * g + 1].z, xv[2 * g + 1].w))};
      sA[bf][xkq * 2 + g][xm] = q;
    }
  };
  auto BLOAD = [&](int kt, uint4* bb) {
#pragma unroll
    for (int kf = 0; kf < 2; ++kf)
#pragma unroll
      for (int ct = 0; ct < 4; ++ct)
        bb[kf * 4 + ct] =
            Wg[(size_t)(kt * 8 + kf * 4 + kcl) * 128 + wc * 64 + ct * 16 + l15];
  };
  auto COMPUTE = [&](int bf, const uint4* bb) {
    uint4 af[2][2];
#pragma unroll
    for (int kf = 0; kf < 2; ++kf)
#pragma unroll
      for (int rt = 0; rt < 2; ++rt)
        af[kf][rt] = sA[bf][kf * 4 + kcl][wr * 32 + rt * 16 + l15];
#pragma unroll
    for (int kf = 0; kf < 2; ++kf)
#pragma unroll
      for (int rt = 0; rt < 2; ++rt)
#pragma unroll
        for (int ct = 0; ct < 4; ++ct)
          acc[rt][ct] = __builtin_amdgcn_mfma_f32_16x16x32_f16(
              as_f16x8(af[kf][rt]), as_f16x8(bb[kf * 4 + ct]), acc[rt][ct], 0, 0, 0);
  };

  XLOAD(0, xva);
  XLOAD(1, xvb);
  BLOAD(0, br0);
  XWRITE(0, xva);
  __syncthreads();

#pragma unroll 1
  for (int kt = 0; kt < GNKT; kt += 2) {
    BLOAD(kt + 1, br1);
    if (kt + 2 < GNKT) XLOAD(kt + 2, xva);
    COMPUTE(0, br0);
    XWRITE(1, xvb);
    __syncthreads();
    if (kt + 2 < GNKT) BLOAD(kt + 2, br0);
    if (kt + 3 < GNKT) XLOAD(kt + 3, xvb);
    COMPUTE(1, br1);
    if (kt + 2 < GNKT) {
      XWRITE(0, xva);
      __syncthreads();
    }
  }

  const int rbase = block_row + wr * 32 + (lane >> 4) * 4;
#pragma unroll
  for (int rt = 0; rt < 2; ++rt)
#pragma unroll
    for (int ct = 0; ct < 4; ++ct) {
      const int col = wc * 64 + ct * 16 + l15;
#pragma unroll
      for (int j = 0; j < 4; ++j) {
        const int row = rbase + rt * 16 + j;
        xw[(size_t)row * HIDDEN + col] = (half_t)(acc[rt][ct][j] + bias_c[ct]);
      }
    }
}

// ---------------------------------------------------------------------------
// Recurrence via MFMA, TWO batch-groups interleaved per block.
// 2 blocks x 32 batch (groups: +0..15, +16..31), 256 threads (4 waves).
// Layout st[buf][group][batch][k]: buf stride 8192 B, GROUP STRIDE 4096 B
// (R12 bug: group offsets used 8192 -> read wrong buffer / wrote past the
// array; fixed here). One barrier per combined step (2 t-advances).
// ---------------------------------------------------------------------------
__global__ __launch_bounds__(256, 1) void rnn_rec_mfma2(
    const half_t* __restrict__ xw, const unsigned int* __restrict__ Whh2,
    const float* __restrict__ W_fc, const float* __restrict__ b_fc,
    float* __restrict__ out) {
  const int blk = blockIdx.x;    // 0..1 -> batch 32-group
  const int tid = threadIdx.x;
  const int lane = tid & 63;
  const int w = tid >> 6;        // wave 0..3 -> h' tiles 2w, 2w+1
  const int bl = lane & 15;      // batch-local 0..15
  const int kg = lane >> 4;      // k-group 0..3
  const int swz = (bl & 7) << 4; // LDS XOR swizzle (bits 4..6)

  // state: [buf][group][batch][k] f16 = 2*2*16*128*2B = 16 KB
  __shared__ half_t st[2][2][RB][HIDDEN];
  __shared__ float red[512];

  uint4 afr[2][4];
#pragma unroll
  for (int mi = 0; mi < 2; ++mi)
#pragma unroll
    for (int kt = 0; kt < 4; ++kt)
      afr[mi][kt] = *(const uint4*)(Whh2 + ((size_t)((2 * w + mi) * 16 + bl)) * 64 +
                                    kt * 16 + kg * 4);

  // zero state buf 0 (both groups)
#pragma unroll
  for (int i = 0; i < 8; ++i) ((unsigned int*)st)[tid + 256 * i] = 0u;
  __syncthreads();

  // xw pointers: [group][mtile]
  const half_t* p00 = xw + ((size_t)(blk * 32 + bl) * TSTEPS) * HIDDEN + w * 32 + kg * 4;
  const half_t* p01 = p00 + 16;
  const half_t* p10 = xw + ((size_t)(blk * 32 + 16 + bl) * TSTEPS) * HIDDEN + w * 32 + kg * 4;
  const half_t* p11 = p10 + 16;

  float hh[2][2][4];  // [group][mtile][j]

  // hoisted LDS byte offsets. GROUP STRIDE = 4096 B.
  int roff0[4], roff1[4];
#pragma unroll
  for (int kt = 0; kt < 4; ++kt) {
    roff0[kt] = ((bl * 256 + kt * 64 + kg * 16) ^ swz);
    roff1[kt] = roff0[kt] + 4096;
  }
  const int w00 = ((bl * 256 + (2 * w + 0) * 32 + kg * 8) ^ swz);
  const int w01 = ((bl * 256 + (2 * w + 1) * 32 + kg * 8) ^ swz);
  const int w10 = w00 + 4096, w11 = w01 + 4096;

  auto STEP2 = [&](const char* stR, char* stW, ushort4 c00, ushort4 c01,
                   ushort4 c10, ushort4 c11) {
    uint4 b0[4], b1[4];
#pragma unroll
    for (int kt = 0; kt < 4; ++kt) b0[kt] = *(const uint4*)(stR + roff0[kt]);
#pragma unroll
    for (int kt = 0; kt < 4; ++kt) b1[kt] = *(const uint4*)(stR + roff1[kt]);

    f32x4 a00, a01, a10, a11;
    a00[0] = h2f(c00.x); a00[1] = h2f(c00.y); a00[2] = h2f(c00.z); a00[3] = h2f(c00.w);
    a01[0] = h2f(c01.x); a01[1] = h2f(c01.y); a01[2] = h2f(c01.z); a01[3] = h2f(c01.w);
    a10[0] = h2f(c10.x); a10[1] = h2f(c10.y); a10[2] = h2f(c10.z); a10[3] = h2f(c10.w);
    a11[0] = h2f(c11.x); a11[1] = h2f(c11.y); a11[2] = h2f(c11.z); a11[3] = h2f(c11.w);

    // 4 independent 4-deep MFMA chains
#pragma unroll
    for (int kt = 0; kt < 4; ++kt) {
      a00 = __builtin_amdgcn_mfma_f32_16x16x32_f16(as_f16x8(afr[0][kt]),
                                                   as_f16x8(b0[kt]), a00, 0, 0, 0);
      a01 = __builtin_amdgcn_mfma_f32_16x16x32_f16(as_f16x8(afr[1][kt]),
                                                   as_f16x8(b0[kt]), a01, 0, 0, 0);
      a10 = __builtin_amdgcn_mfma_f32_16x16x32_f16(as_f16x8(afr[0][kt]),
                                                   as_f16x8(b1[kt]), a10, 0, 0, 0);
      a11 = __builtin_amdgcn_mfma_f32_16x16x32_f16(as_f16x8(afr[1][kt]),
                                                   as_f16x8(b1[kt]), a11, 0, 0, 0);
    }
#pragma unroll
    for (int j = 0; j < 4; ++j) {
      hh[0][0][j] = tanh_fast(a00[j]);
      hh[0][1][j] = tanh_fast(a01[j]);
      hh[1][0][j] = tanh_fast(a10[j]);
      hh[1][1][j] = tanh_fast(a11[j]);
    }
    uint2 q00 = {h2u(pkrtz(hh[0][0][0], hh[0][0][1])), h2u(pkrtz(hh[0][0][2], hh[0][0][3]))};
    uint2 q01 = {h2u(pkrtz(hh[0][1][0], hh[0][1][1])), h2u(pkrtz(hh[0][1][2], hh[0][1][3]))};
    uint2 q10 = {h2u(pkrtz(hh[1][0][0], hh[1][0][1])), h2u(pkrtz(hh[1][0][2], hh[1][0][3]))};
    uint2 q11 = {h2u(pkrtz(hh[1][1][0], hh[1][1][1])), h2u(pkrtz(hh[1][1][2], hh[1][1][3]))};
    *(uint2*)(stW + w00) = q00;
    *(uint2*)(stW + w01) = q01;
    *(uint2*)(stW + w10) = q10;
    *(uint2*)(stW + w11) = q11;
    __syncthreads();
  };

  char* st0 = (char*)&st[0][0][0][0];
  char* st1 = (char*)&st[1][0][0][0];

  ushort4 xa00 = *(const ushort4*)(p00);
  ushort4 xa01 = *(const ushort4*)(p01);
  ushort4 xa10 = *(const ushort4*)(p10);
  ushort4 xa11 = *(const ushort4*)(p11);
  ushort4 xb00 = *(const ushort4*)(p00 + HIDDEN);
  ushort4 xb01 = *(const ushort4*)(p01 + HIDDEN);
  ushort4 xb10 = *(const ushort4*)(p10 + HIDDEN);
  ushort4 xb11 = *(const ushort4*)(p11 + HIDDEN);

  for (int t2 = 0; t2 < TSTEPS; t2 += 2) {
    const ushort4 c00 = xa00, c01 = xa01, c10 = xa10, c11 = xa11;
    xa00 = *(const ushort4*)(p00 + (size_t)(t2 + 2) * HIDDEN);
    xa01 = *(const ushort4*)(p01 + (size_t)(t2 + 2) * HIDDEN);
    xa10 = *(const ushort4*)(p10 + (size_t)(t2 + 2) * HIDDEN);
    xa11 = *(const ushort4*)(p11 + (size_t)(t2 + 2) * HIDDEN);
    STEP2(st0, st1, c00, c01, c10, c11);

    const ushort4 d00 = xb00, d01 = xb01, d10 = xb10, d11 = xb11;
    xb00 = *(const ushort4*)(p00 + (size_t)(t2 + 3) * HIDDEN);
    xb01 = *(const ushort4*)(p01 + (size_t)(t2 + 3) * HIDDEN);
    xb10 = *(const ushort4*)(p10 + (size_t)(t2 + 3) * HIDDEN);
    xb11 = *(const ushort4*)(p11 + (size_t)(t2 + 3) * HIDDEN);
    STEP2(st1, st0, d00, d01, d10, d11);
  }

  // fused FC for both groups
  const float4 wf0 = *(const float4*)&W_fc[(2 * w + 0) * 16 + kg * 4];
  const float4 wf1 = *(const float4*)&W_fc[(2 * w + 1) * 16 + kg * 4];
  float part0 = hh[0][0][0] * wf0.x + hh[0][0][1] * wf0.y + hh[0][0][2] * wf0.z +
                hh[0][0][3] * wf0.w + hh[0][1][0] * wf1.x + hh[0][1][1] * wf1.y +
                hh[0][1][2] * wf1.z + hh[0][1][3] * wf1.w;
  float part1 = hh[1][0][0] * wf0.x + hh[1][0][1] * wf0.y + hh[1][0][2] * wf0.z +
                hh[1][0][3] * wf0.w + hh[1][1][0] * wf1.x + hh[1][1][1] * wf1.y +
                hh[1][1][2] * wf1.z + hh[1][1][3] * wf1.w;
  red[tid] = part0;
  red[256 + tid] = part1;
  __syncthreads();
  if (tid < RB) {
    float s = b_fc[0];
#pragma unroll
    for (int q = 0; q < 16; ++q) s += red[q * 16 + tid];
    out[blk * 32 + tid] = s;
  } else if (tid < 32) {
    const int b2 = tid - 16;
    float s = b_fc[0];
#pragma unroll
    for (int q = 0; q < 16; ++q) s += red[256 + q * 16 + b2];
    out[blk * 32 + 16 + b2] = s;
  }
}

extern "C" void kernel_launch(void* const* d_in, const int* in_sizes, int n_in,
                              void* d_out, int out_size, void* d_ws, size_t ws_size,
                              hipStream_t stream) {
  const float* x    = (const float*)d_in[0];
  const float* W_ih = (const float*)d_in[1];
  const float* W_hh = (const float*)d_in[2];
  const float* b_ih = (const float*)d_in[3];
  const float* b_hh = (const float*)d_in[4];
  const float* W_fc = (const float*)d_in[5];
  const float* b_fc = (const float*)d_in[6];

  char* ws = (char*)d_ws;
  half_t*       xwf16 = (half_t*)ws;                                     // 8 MB
  uint4*        Wg    = (uint4*)(ws + (8u << 20));                       // 512 KB
  unsigned int* Whh2  = (unsigned int*)(ws + (8u << 20) + (512u << 10)); // 32 KB

  prep_kernel<<<128, 256, 0, stream>>>(W_ih, W_hh, Wg, Whh2);
  gemm_xw_f16<<<(BATCH * TSTEPS) / GBM, 256, 0, stream>>>(x, Wg, b_ih, b_hh, xwf16);
  rnn_rec_mfma2<<<2, 256, 0, stream>>>(xwf16, Whh2, W_fc, b_fc, (float*)d_out);
}